// Round 6
// baseline (7974.440 us; speedup 1.0000x reference)
//
#include <hip/hip_runtime.h>
#include <math.h>

typedef __bf16 bf16x8 __attribute__((ext_vector_type(8)));
typedef float f32x4 __attribute__((ext_vector_type(4)));
typedef float f32x8 __attribute__((ext_vector_type(8)));

__device__ __forceinline__ float clampf(float x, float lo, float hi) {
    return fminf(fmaxf(x, lo), hi);
}

__global__ void zero_ints(int* __restrict__ p, int n) {
    int i = blockIdx.x * 256 + threadIdx.x;
    if (i < n) p[i] = 0;
}

// Pack W into MFMA B-frag layout, bf16.
// Wb[((t*KSTEPS + s)*64 + l)*8 + j] = W[k = s*32 + (l>>4)*8 + j][co = t*16 + (l&15)]
// W rows: k < 64*CIN -> cw flat [64*CIN][COUT]; k >= 64*CIN (DENSE) -> fw[k-64*CIN][COUT]
__global__ void repack_wb(const float* __restrict__ cw, const float* __restrict__ fw,
                          unsigned short* __restrict__ Wb, int CIN, int COUT, int COTILES,
                          int DENSE) {
    int idx = blockIdx.x * 256 + threadIdx.x;
    int KT = (DENSE ? 65 : 64) * CIN;
    int KSTEPS = KT / 32;
    int total = COTILES * KSTEPS * 512;
    if (idx >= total) return;
    int j = idx & 7;
    int l = (idx >> 3) & 63;
    int rest = idx >> 9;
    int s = rest % KSTEPS;
    int t = rest / KSTEPS;
    int k = s * 32 + (l >> 4) * 8 + j;
    int co = t * 16 + (l & 15);
    float v = 0.f;
    if (co < COUT) {
        if (k < 64 * CIN) v = cw[k * COUT + co];
        else v = fw[(k - 64 * CIN) * COUT + co];
    }
    __bf16 h = (__bf16)v;
    Wb[idx] = __builtin_bit_cast(unsigned short, h);
}

__global__ void edge_hist(const int* __restrict__ ei, const int* __restrict__ ej,
                          int* __restrict__ counts, int E) {
    int e = blockIdx.x * 256 + threadIdx.x;
    if (e >= E) return;
    int i = ei[e], j = ej[e];
    if (i != j) atomicAdd(&counts[i], 1);
}

__global__ __launch_bounds__(1024) void scan_kernel(const int* __restrict__ counts,
                                                    int* __restrict__ offs,
                                                    int* __restrict__ cursor, int N) {
    __shared__ int sums[1024];
    const int t = threadIdx.x;
    const int per = (N + 1023) / 1024;
    const int lo = t * per;
    const int hi = min(lo + per, N);
    int s = 0;
    for (int i = lo; i < hi; ++i) s += counts[i];
    sums[t] = s;
    __syncthreads();
    for (int d = 1; d < 1024; d <<= 1) {
        int v = (t >= d) ? sums[t - d] : 0;
        __syncthreads();
        sums[t] += v;
        __syncthreads();
    }
    int run = (t > 0) ? sums[t - 1] : 0;
    for (int i = lo; i < hi; ++i) {
        offs[i] = run;
        cursor[i] = run;
        run += counts[i];
    }
    if (t == 1023) offs[N] = sums[1023];
}

// csr_jk pack: j[0:17) | iu[20:23) | iv[23:26)
__global__ void edge_scatter(const int* __restrict__ ei, const int* __restrict__ ej,
                             const float* __restrict__ pos, int* __restrict__ cursor,
                             int* __restrict__ csr_jk, float2* __restrict__ csr_w, int E) {
    int e = blockIdx.x * 256 + threadIdx.x;
    if (e >= E) return;
    int i = ei[e], j = ej[e];
    if (i == j) return;
    float dx = clampf(pos[i * 2 + 0] - pos[j * 2 + 0], -1.f, 1.f);
    float dy = clampf(pos[i * 2 + 1] - pos[j * 2 + 1], -1.f, 1.f);
    float r = sqrtf(dx * dx + dy * dy + 1e-12f);
    float u = clampf(2.f * r - 1.f, -1.f, 1.f);
    float v = atan2f(dy, dx) * 0.3183098861837907f;  // / pi
    float tu = (u + 1.f) * 3.5f;
    float tv = (v + 1.f) * 3.5f;
    int iu = min(6, max(0, (int)floorf(tu)));
    int iv = min(6, max(0, (int)floorf(tv)));
    float fu = clampf(tu - (float)iu, 0.f, 1.f);
    float fv = clampf(tv - (float)iv, 0.f, 1.f);
    int p = atomicAdd(&cursor[i], 1);
    csr_jk[p] = j | (iu << 20) | (iv << 23);
    csr_w[p] = make_float2(fu, fv);
}

__device__ __forceinline__ bf16x8 frag_from_lds(const float* arow, int s, int quad) {
    const float4* ap = (const float4*)(arow + s * 32 + quad * 8);
    float4 a0 = ap[0], a1 = ap[1];
    f32x8 av = {a0.x, a0.y, a0.z, a0.w, a1.x, a1.y, a1.z, a1.w};
    return __builtin_convertvector(av, bf16x8);
}

// 256 threads = 4 waves; TM=4 nodes/block; wave w privately owns node base+w in
// the scatter. Scatter accumulates via fire-and-forget ds_add_f32 atomics (no
// read-modify-write latency chain; wave-private rows -> no cross-wave
// same-address collisions). CIN=4 runs 16 edges per wave-op (lane = edge x ch).
// Contraction: K split across the 4 waves, each wave does ALL co-tiles for its
// K-quarter (each A-frag converted once), then LDS cross-wave reduce.
// MODE 0: layer0 (no relu; out = [lin 0..31 | conv 32..63]); waves 0,1 conv, 2,3 lin
// MODE 1: relu in, out = conv(+dense row folded) + cb + fb
// MODE 2: MODE1 + residual x
// MODE 3: relu in, COUT=2; 4-way K-split + LDS reduce, /128
template <int CIN, int COTILES, int MODE>
__global__ __launch_bounds__(256) void conv_mfma(
    const float* __restrict__ x, const unsigned short* __restrict__ Wb,
    const float* __restrict__ cb, const float* __restrict__ fb, const float* __restrict__ fw,
    const int* __restrict__ offs, const int* __restrict__ csr_jk,
    const float2* __restrict__ csr_w, float* __restrict__ out, int nNodes) {
    constexpr int TM = 4;
    constexpr int KT = (MODE == 0 ? 64 * CIN : 65 * CIN);
    constexpr int KSTEPS = KT / 32;
    constexpr int RS = KT + 12;
    extern __shared__ float mom[];
    const int tid = threadIdx.x;
    const int w = tid >> 6;
    const int lane = tid & 63;
    const int base = blockIdx.x * TM;
    const int n = base + w;

    {  // zero moments
        float4 z = make_float4(0.f, 0.f, 0.f, 0.f);
        float4* m4 = (float4*)mom;
        const int tot4 = TM * RS / 4;
        for (int i = tid; i < tot4; i += 256) m4[i] = z;
    }
    __syncthreads();

    // ---- scatter: wave-private rows, ds_add atomics (no RMW chain)
    if (n < nNodes) {
        const int s0e = offs[n], e1 = offs[n + 1];
        float* momn = mom + w * RS;
        constexpr int EPL = 64 / CIN;              // edges per wave-op (1 or 16)
        constexpr int U = (CIN == 64) ? 8 : 2;     // per-lane register batch
        const int c = lane & (CIN - 1);
        const int sub = lane / CIN;                // 0..EPL-1
        for (int b = s0e; b < e1; b += U * EPL) {
            int jk[U];
            float fu[U], fv[U], xv[U];
#pragma unroll
            for (int u = 0; u < U; ++u) {
                int e = b + sub * U + u;
                bool ok = e < e1;
                int ee = ok ? e : s0e;
                jk[u] = csr_jk[ee];
                float2 wv = csr_w[ee];
                fu[u] = wv.x;
                fv[u] = wv.y;
                xv[u] = ok ? 1.f : 0.f;
            }
#pragma unroll
            for (int u = 0; u < U; ++u) {
                int j = jk[u] & 0x1FFFF;
                float v = x[j * CIN + c];
                if (MODE >= 1) v = fmaxf(v, 0.f);
                xv[u] *= v;
            }
#pragma unroll
            for (int u = 0; u < U; ++u) {
                int iu = (jk[u] >> 20) & 7;
                int iv = (jk[u] >> 23) & 7;
                float gu = 1.f - fu[u], gv = 1.f - fv[u];
                float* p = momn + (iu * 8 + iv) * CIN + c;
                atomicAdd(p, gu * gv * xv[u]);
                atomicAdd(p + CIN, gu * fv[u] * xv[u]);
                atomicAdd(p + 8 * CIN, fu[u] * gv * xv[u]);
                atomicAdd(p + 9 * CIN, fu[u] * fv[u] * xv[u]);
            }
        }
        if (MODE >= 1) {  // dense row (k = 64*CIN + lane), CIN==64
            momn[64 * CIN + lane] = fmaxf(x[n * CIN + lane], 0.f);
        }
    }
    __syncthreads();

    // ---- MFMA contraction; C rows 4..15 are harmless duplicates (never stored)
    const int row = lane & 15;
    const int quad = lane >> 4;
    const float* arow = mom + (row & 3) * RS;

    if (MODE == 1 || MODE == 2) {
        // wave w: K-range [s0, s_end), all 4 co-tiles
        const int s0 = w * ((KSTEPS + 3) / 4);
        const int s_end = min(s0 + (KSTEPS + 3) / 4, KSTEPS);
        const uint4* Bp = (const uint4*)Wb;
        f32x4 acc[4] = {{0, 0, 0, 0}, {0, 0, 0, 0}, {0, 0, 0, 0}, {0, 0, 0, 0}};
        uint4 b0[4], b1[4];
#pragma unroll
        for (int t = 0; t < 4; ++t) {
            b0[t] = (s0 < s_end) ? Bp[((size_t)t * KSTEPS + s0) * 64 + lane] : make_uint4(0, 0, 0, 0);
            b1[t] = (s0 + 1 < s_end) ? Bp[((size_t)t * KSTEPS + s0 + 1) * 64 + lane]
                                     : make_uint4(0, 0, 0, 0);
        }
        for (int s = s0; s < s_end; ++s) {
            uint4 bq[4];
#pragma unroll
            for (int t = 0; t < 4; ++t) {
                bq[t] = b0[t];
                b0[t] = b1[t];
                if (s + 2 < s_end) b1[t] = Bp[((size_t)t * KSTEPS + s + 2) * 64 + lane];
            }
            bf16x8 a = frag_from_lds(arow, s, quad);
#pragma unroll
            for (int t = 0; t < 4; ++t)
                acc[t] = __builtin_amdgcn_mfma_f32_16x16x32_bf16(
                    a, __builtin_bit_cast(bf16x8, bq[t]), acc[t], 0, 0, 0);
        }
        __syncthreads();
        f32x4* red = (f32x4*)mom;
#pragma unroll
        for (int t = 0; t < 4; ++t) red[(w * 4 + t) * 64 + lane] = acc[t];
        __syncthreads();
        // wave w reduces co-tile w
        f32x4 s = red[w * 64 + lane] + red[(4 + w) * 64 + lane] + red[(8 + w) * 64 + lane] +
                  red[(12 + w) * 64 + lane];
        if (lane < 16) {
            const int co = w * 16 + lane;
#pragma unroll
            for (int i = 0; i < 4; ++i) {
                int nn = base + i;
                if (nn < nNodes) {
                    float res = s[i] + cb[co] + fb[co];
                    if (MODE == 2) res += x[nn * 64 + co];
                    out[nn * 64 + co] = res;
                }
            }
        }
    } else if (MODE == 3) {
        const int s0 = w * ((KSTEPS + 3) / 4);
        const int s_end = min(s0 + (KSTEPS + 3) / 4, KSTEPS);
        const uint4* Bp = (const uint4*)Wb;
        f32x4 acc = {0, 0, 0, 0};
        uint4 b0 = (s0 < s_end) ? Bp[(size_t)s0 * 64 + lane] : make_uint4(0, 0, 0, 0);
        uint4 b1 = (s0 + 1 < s_end) ? Bp[(size_t)(s0 + 1) * 64 + lane] : make_uint4(0, 0, 0, 0);
        uint4 b2 = (s0 + 2 < s_end) ? Bp[(size_t)(s0 + 2) * 64 + lane] : make_uint4(0, 0, 0, 0);
        uint4 b3 = (s0 + 3 < s_end) ? Bp[(size_t)(s0 + 3) * 64 + lane] : make_uint4(0, 0, 0, 0);
        for (int s = s0; s < s_end; ++s) {
            uint4 bq = b0;
            b0 = b1;
            b1 = b2;
            b2 = b3;
            if (s + 4 < s_end) b3 = Bp[(size_t)(s + 4) * 64 + lane];
            bf16x8 a = frag_from_lds(arow, s, quad);
            acc = __builtin_amdgcn_mfma_f32_16x16x32_bf16(a, __builtin_bit_cast(bf16x8, bq), acc,
                                                          0, 0, 0);
        }
        __syncthreads();
        f32x4* red = (f32x4*)mom;
        red[w * 64 + lane] = acc;
        __syncthreads();
        if (w == 0 && lane < 16) {
            f32x4 s = red[lane] + red[64 + lane] + red[128 + lane] + red[192 + lane];
            const int co = lane;
            if (co < 2) {
#pragma unroll
                for (int i = 0; i < 4; ++i) {
                    int nn = base + i;
                    if (nn < nNodes) out[nn * 2 + co] = (s[i] + cb[co] + fb[co]) * (1.f / 128.f);
                }
            }
        }
    } else {  // MODE 0
        if (w < COTILES) {
            const uint4* Bp = (const uint4*)Wb + (size_t)w * KSTEPS * 64;
            f32x4 acc = {0, 0, 0, 0};
            uint4 b0 = Bp[lane], b1 = Bp[64 + lane], b2 = Bp[128 + lane], b3 = Bp[192 + lane];
            for (int s = 0; s < KSTEPS; ++s) {
                uint4 bq = b0;
                b0 = b1;
                b1 = b2;
                b2 = b3;
                if (s + 4 < KSTEPS) b3 = Bp[(size_t)(s + 4) * 64 + lane];
                bf16x8 a = frag_from_lds(arow, s, quad);
                acc = __builtin_amdgcn_mfma_f32_16x16x32_bf16(a, __builtin_bit_cast(bf16x8, bq),
                                                              acc, 0, 0, 0);
            }
            if (lane < 16) {
                const int co = w * 16 + lane;
#pragma unroll
                for (int i = 0; i < 4; ++i) {
                    int nn = base + i;
                    if (nn < nNodes) out[nn * 64 + 32 + co] = acc[i] + cb[co];
                }
            }
        } else {
            // waves 2,3: dense lin branch -> cols 0..31 (no relu on layer-0 input)
            const int co = lane & 31;
            const int r = (w - 2) * 2 + (lane >> 5);
            int nn = base + r;
            if (nn < nNodes) {
                const float4 xr = *(const float4*)(x + nn * 4);
                float sdot = xr.x * fw[co] + xr.y * fw[32 + co] + xr.z * fw[64 + co] +
                             xr.w * fw[96 + co] + fb[co];
                out[nn * 64 + co] = sdot;
            }
        }
    }
}

extern "C" void kernel_launch(void* const* d_in, const int* in_sizes, int n_in,
                              void* d_out, int out_size, void* d_ws, size_t ws_size,
                              hipStream_t stream) {
    const float* pos = (const float*)d_in[0];
    const float* feat = (const float*)d_in[1];
    const int* ei = (const int*)d_in[2];
    const int* ej = (const int*)d_in[3];
    const float* cw0 = (const float*)d_in[4];
    const float* cb0 = (const float*)d_in[5];
    const float* fw0 = (const float*)d_in[6];
    const float* fb0 = (const float*)d_in[7];
    const float* cw1 = (const float*)d_in[8];
    const float* cb1 = (const float*)d_in[9];
    const float* fw1 = (const float*)d_in[10];
    const float* fb1 = (const float*)d_in[11];
    const float* cw2 = (const float*)d_in[12];
    const float* cb2 = (const float*)d_in[13];
    const float* fw2 = (const float*)d_in[14];
    const float* fb2 = (const float*)d_in[15];
    const float* cw3 = (const float*)d_in[16];
    const float* cb3 = (const float*)d_in[17];
    const float* fw3 = (const float*)d_in[18];
    const float* fb3 = (const float*)d_in[19];
    float* outp = (float*)d_out;

    const int N = in_sizes[0] / 2;
    const int E = in_sizes[2];

    char* wsp = (char*)d_ws;
    size_t off = 0;
    auto alloc = [&](size_t bytes) -> void* {
        void* p = wsp + off;
        off = (off + bytes + 255) & ~(size_t)255;
        return p;
    };
    int* counts = (int*)alloc((size_t)N * 4);
    int* offs = (int*)alloc((size_t)(N + 1) * 4);
    int* cursor = (int*)alloc((size_t)N * 4);
    int* csr_jk = (int*)alloc((size_t)E * 4);
    float2* csr_w = (float2*)alloc((size_t)E * 8);
    float* ansA = (float*)alloc((size_t)N * 64 * 4);
    float* ansB = (float*)alloc((size_t)N * 64 * 4);
    unsigned short* Wb0 = (unsigned short*)alloc((size_t)2 * 8 * 512 * 2);
    unsigned short* Wb1 = (unsigned short*)alloc((size_t)4 * 130 * 512 * 2);
    unsigned short* Wb2 = (unsigned short*)alloc((size_t)4 * 130 * 512 * 2);
    unsigned short* Wb3 = (unsigned short*)alloc((size_t)1 * 130 * 512 * 2);
    (void)ws_size;
    (void)n_in;
    (void)out_size;

    const int BIG_LDS = 4 * (65 * 64 + 12) * 4;   // 66752 B -> 2 blocks/CU
    const int SMALL_LDS = 4 * (64 * 4 + 12) * 4;  // 4288 B
    hipFuncSetAttribute((const void*)&conv_mfma<64, 4, 1>,
                        hipFuncAttributeMaxDynamicSharedMemorySize, BIG_LDS);
    hipFuncSetAttribute((const void*)&conv_mfma<64, 4, 2>,
                        hipFuncAttributeMaxDynamicSharedMemorySize, BIG_LDS);
    hipFuncSetAttribute((const void*)&conv_mfma<64, 1, 3>,
                        hipFuncAttributeMaxDynamicSharedMemorySize, BIG_LDS);

    zero_ints<<<dim3((N + 255) / 256), dim3(256), 0, stream>>>(counts, N);
    repack_wb<<<dim3((2 * 8 * 512 + 255) / 256), dim3(256), 0, stream>>>(cw0, fw0, Wb0, 4, 32, 2, 0);
    repack_wb<<<dim3((4 * 130 * 512 + 255) / 256), dim3(256), 0, stream>>>(cw1, fw1, Wb1, 64, 64, 4, 1);
    repack_wb<<<dim3((4 * 130 * 512 + 255) / 256), dim3(256), 0, stream>>>(cw2, fw2, Wb2, 64, 64, 4, 1);
    repack_wb<<<dim3((1 * 130 * 512 + 255) / 256), dim3(256), 0, stream>>>(cw3, fw3, Wb3, 64, 2, 1, 1);
    edge_hist<<<dim3((E + 255) / 256), dim3(256), 0, stream>>>(ei, ej, counts, E);
    scan_kernel<<<dim3(1), dim3(1024), 0, stream>>>(counts, offs, cursor, N);
    edge_scatter<<<dim3((E + 255) / 256), dim3(256), 0, stream>>>(ei, ej, pos, cursor, csr_jk,
                                                                  csr_w, E);

    const int nb = (N + 3) / 4;
    conv_mfma<4, 2, 0><<<dim3(nb), dim3(256), SMALL_LDS, stream>>>(
        feat, Wb0, cb0, fb0, fw0, offs, csr_jk, csr_w, ansA, N);
    conv_mfma<64, 4, 1><<<dim3(nb), dim3(256), BIG_LDS, stream>>>(
        ansA, Wb1, cb1, fb1, fw1, offs, csr_jk, csr_w, ansB, N);
    conv_mfma<64, 4, 2><<<dim3(nb), dim3(256), BIG_LDS, stream>>>(
        ansB, Wb2, cb2, fb2, fw2, offs, csr_jk, csr_w, ansA, N);
    conv_mfma<64, 2, 3><<<dim3(nb), dim3(256), BIG_LDS, stream>>>(
        ansA, Wb3, cb3, fb3, fw3, offs, csr_jk, csr_w, outp, N);
}

// Round 7
// 2295.858 us; speedup vs baseline: 3.4734x; 3.4734x over previous
//
#include <hip/hip_runtime.h>
#include <math.h>

typedef __bf16 bf16x8 __attribute__((ext_vector_type(8)));
typedef float f32x4 __attribute__((ext_vector_type(4)));
typedef float f32x8 __attribute__((ext_vector_type(8)));

__device__ __forceinline__ float clampf(float x, float lo, float hi) {
    return fminf(fmaxf(x, lo), hi);
}

__global__ void zero_ints(int* __restrict__ p, int n) {
    int i = blockIdx.x * 256 + threadIdx.x;
    if (i < n) p[i] = 0;
}

// Pack W into MFMA B-frag layout, bf16.
// Wb[((t*KSTEPS + s)*64 + l)*8 + j] = W[k = s*32 + (l>>4)*8 + j][co = t*16 + (l&15)]
__global__ void repack_wb(const float* __restrict__ cw, const float* __restrict__ fw,
                          unsigned short* __restrict__ Wb, int CIN, int COUT, int COTILES,
                          int DENSE) {
    int idx = blockIdx.x * 256 + threadIdx.x;
    int KT = (DENSE ? 65 : 64) * CIN;
    int KSTEPS = KT / 32;
    int total = COTILES * KSTEPS * 512;
    if (idx >= total) return;
    int j = idx & 7;
    int l = (idx >> 3) & 63;
    int rest = idx >> 9;
    int s = rest % KSTEPS;
    int t = rest / KSTEPS;
    int k = s * 32 + (l >> 4) * 8 + j;
    int co = t * 16 + (l & 15);
    float v = 0.f;
    if (co < COUT) {
        if (k < 64 * CIN) v = cw[k * COUT + co];
        else v = fw[(k - 64 * CIN) * COUT + co];
    }
    __bf16 h = (__bf16)v;
    Wb[idx] = __builtin_bit_cast(unsigned short, h);
}

__global__ void edge_hist(const int* __restrict__ ei, const int* __restrict__ ej,
                          int* __restrict__ counts, int E) {
    int e = blockIdx.x * 256 + threadIdx.x;
    if (e >= E) return;
    int i = ei[e], j = ej[e];
    if (i != j) atomicAdd(&counts[i], 1);
}

__global__ __launch_bounds__(1024) void scan_kernel(const int* __restrict__ counts,
                                                    int* __restrict__ offs,
                                                    int* __restrict__ cursor, int N) {
    __shared__ int sums[1024];
    const int t = threadIdx.x;
    const int per = (N + 1023) / 1024;
    const int lo = t * per;
    const int hi = min(lo + per, N);
    int s = 0;
    for (int i = lo; i < hi; ++i) s += counts[i];
    sums[t] = s;
    __syncthreads();
    for (int d = 1; d < 1024; d <<= 1) {
        int v = (t >= d) ? sums[t - d] : 0;
        __syncthreads();
        sums[t] += v;
        __syncthreads();
    }
    int run = (t > 0) ? sums[t - 1] : 0;
    for (int i = lo; i < hi; ++i) {
        offs[i] = run;
        cursor[i] = run;
        run += counts[i];
    }
    if (t == 1023) offs[N] = sums[1023];
}

// csr_jk pack: j[0:17) | iu[20:23) | iv[23:26)
__global__ void edge_scatter(const int* __restrict__ ei, const int* __restrict__ ej,
                             const float* __restrict__ pos, int* __restrict__ cursor,
                             int* __restrict__ csr_jk, float2* __restrict__ csr_w, int E) {
    int e = blockIdx.x * 256 + threadIdx.x;
    if (e >= E) return;
    int i = ei[e], j = ej[e];
    if (i == j) return;
    float dx = clampf(pos[i * 2 + 0] - pos[j * 2 + 0], -1.f, 1.f);
    float dy = clampf(pos[i * 2 + 1] - pos[j * 2 + 1], -1.f, 1.f);
    float r = sqrtf(dx * dx + dy * dy + 1e-12f);
    float u = clampf(2.f * r - 1.f, -1.f, 1.f);
    float v = atan2f(dy, dx) * 0.3183098861837907f;  // / pi
    float tu = (u + 1.f) * 3.5f;
    float tv = (v + 1.f) * 3.5f;
    int iu = min(6, max(0, (int)floorf(tu)));
    int iv = min(6, max(0, (int)floorf(tv)));
    float fu = clampf(tu - (float)iu, 0.f, 1.f);
    float fv = clampf(tv - (float)iv, 0.f, 1.f);
    int p = atomicAdd(&cursor[i], 1);
    csr_jk[p] = j | (iu << 20) | (iv << 23);
    csr_w[p] = make_float2(fu, fv);
}

__device__ __forceinline__ bf16x8 frag_from_lds(const float* arow, int s, int quad) {
    const float4* ap = (const float4*)(arow + s * 32 + quad * 8);
    float4 a0 = ap[0], a1 = ap[1];
    f32x8 av = {a0.x, a0.y, a0.z, a0.w, a1.x, a1.y, a1.z, a1.w};
    return __builtin_convertvector(av, bf16x8);
}

// ---------------------------------------------------------------------------
// Layers 1..3 (CIN=64). 1024 threads = 16 waves, TM=4 nodes.
// Scatter: per node 4 waves = {edge-half h} x {tap-row-parity p}. Copy h is a
// private LDS moment row (race-free: halves are disjoint edge sets, parities
// own disjoint bin rows). Plain RMW (NO ds atomics: 3x slower, round 6).
// Then copy reduce, then 16-way K-split MFMA GEMM with LDS partial reduce.
// MODE 1: relu in, out = conv(+dense row) + cb + fb
// MODE 2: MODE1 + residual x
// MODE 3: relu in, COUT=2 (1 co-tile), /128
template <int MODE>
__global__ __launch_bounds__(1024, 4) void conv64_mfma(
    const float* __restrict__ x, const unsigned short* __restrict__ Wb,
    const float* __restrict__ cb, const float* __restrict__ fb,
    const int* __restrict__ offs, const int* __restrict__ csr_jk,
    const float2* __restrict__ csr_w, float* __restrict__ out, int nNodes) {
    constexpr int TM = 4;
    constexpr int KT = 65 * 64;        // 4160
    constexpr int KSTEPS = KT / 32;    // 130
    constexpr int RS = KT + 12;        // 4172
    extern __shared__ float mom[];     // [8][RS]: rows 0..3 copy0, 4..7 copy1
    const int tid = threadIdx.x;
    const int w = tid >> 6;
    const int lane = tid & 63;
    const int node = w >> 2;
    const int h = (w >> 1) & 1;  // edge half
    const int p = w & 1;         // tap-row parity
    const int base = blockIdx.x * TM;
    const int n = base + node;

    {  // zero both copies
        float4 z = make_float4(0.f, 0.f, 0.f, 0.f);
        float4* m4 = (float4*)mom;
        const int tot4 = 8 * RS / 4;
        for (int i = tid; i < tot4; i += 1024) m4[i] = z;
    }
    __syncthreads();

    // ---- scatter
    if (n < nNodes) {
        const int e0 = offs[n], e1 = offs[n + 1];
        const int len = e1 - e0;
        const int hl = (len + 1) >> 1;
        const int bs = e0 + h * hl;
        const int be = min(bs + hl, e1);
        float* momn = mom + (h * 4 + node) * RS;
        const int c = lane;
        for (int b = bs; b < be; b += 8) {
            int jk[8];
            float fu[8], fv[8], xv[8];
#pragma unroll
            for (int u = 0; u < 8; ++u) {
                int e = b + u;
                bool ok = e < be;
                int ee = ok ? e : bs;
                jk[u] = csr_jk[ee];
                float2 wv = csr_w[ee];
                fu[u] = wv.x;
                fv[u] = wv.y;
                xv[u] = ok ? 1.f : 0.f;
            }
#pragma unroll
            for (int u = 0; u < 8; ++u) {
                int j = jk[u] & 0x1FFFF;
                xv[u] *= fmaxf(x[j * 64 + c], 0.f);
            }
#pragma unroll
            for (int u = 0; u < 8; ++u) {
                int iu = (jk[u] >> 20) & 7;
                int iv = (jk[u] >> 23) & 7;
                bool sel = ((iu & 1) == p);
                int rowi = sel ? iu : iu + 1;
                float wu = sel ? (1.f - fu[u]) : fu[u];
                float gv = 1.f - fv[u];
                float* pp = momn + (rowi * 8 + iv) * 64 + c;
                pp[0] += wu * gv * xv[u];
                pp[64] += wu * fv[u] * xv[u];
            }
        }
        if ((w & 3) == 0) {  // dense row k = 4096 + lane, into copy 0
            mom[node * RS + 4096 + lane] = fmaxf(x[n * 64 + lane], 0.f);
        }
    }
    __syncthreads();

    // ---- reduce copy1 into copy0 (dense slot in copy1 is zero)
    {
        constexpr int T4 = KT / 4;  // 1040 float4 per row
        for (int idx = tid; idx < TM * T4; idx += 1024) {
            int r = idx / T4, off = idx - r * T4;
            float4* a = (float4*)(mom + r * RS) + off;
            const float4* bptr = (const float4*)(mom + (4 + r) * RS) + off;
            float4 av = *a, bv = *bptr;
            av.x += bv.x; av.y += bv.y; av.z += bv.z; av.w += bv.w;
            *a = av;
        }
    }
    __syncthreads();

    // ---- GEMM: 16-way K-split; partials into copy1 region
    const int row = lane & 15;
    const int quad = lane >> 4;
    const float* arow = mom + (row & 3) * RS;
    f32x4* red = (f32x4*)(mom + 4 * RS);
    constexpr int CHUNK = (KSTEPS + 15) / 16;  // 9
    const int s0 = w * CHUNK;
    const int s_end = min(s0 + CHUNK, KSTEPS);

    if (MODE == 3) {
        const uint4* Bp = (const uint4*)Wb;
        f32x4 acc = {0, 0, 0, 0};
        uint4 b0 = make_uint4(0, 0, 0, 0), b1 = b0, b2 = b0, b3 = b0;
        if (s0 + 0 < s_end) b0 = Bp[(size_t)(s0 + 0) * 64 + lane];
        if (s0 + 1 < s_end) b1 = Bp[(size_t)(s0 + 1) * 64 + lane];
        if (s0 + 2 < s_end) b2 = Bp[(size_t)(s0 + 2) * 64 + lane];
        if (s0 + 3 < s_end) b3 = Bp[(size_t)(s0 + 3) * 64 + lane];
        for (int s = s0; s < s_end; ++s) {
            uint4 bq = b0;
            b0 = b1; b1 = b2; b2 = b3;
            if (s + 4 < s_end) b3 = Bp[(size_t)(s + 4) * 64 + lane];
            bf16x8 a = frag_from_lds(arow, s, quad);
            acc = __builtin_amdgcn_mfma_f32_16x16x32_bf16(a, __builtin_bit_cast(bf16x8, bq), acc,
                                                          0, 0, 0);
        }
        red[w * 64 + lane] = acc;
        __syncthreads();
        if (w == 0 && lane < 16) {
            f32x4 s = {0, 0, 0, 0};
#pragma unroll
            for (int g = 0; g < 16; ++g) s += red[g * 64 + lane];
            const int co = lane;
            if (co < 2) {
#pragma unroll
                for (int i = 0; i < 4; ++i) {
                    int nn = base + i;
                    if (nn < nNodes) out[nn * 2 + co] = (s[i] + cb[co] + fb[co]) * (1.f / 128.f);
                }
            }
        }
    } else {
        const uint4* Bp = (const uint4*)Wb;
        f32x4 acc[4] = {{0, 0, 0, 0}, {0, 0, 0, 0}, {0, 0, 0, 0}, {0, 0, 0, 0}};
        uint4 b0[4], b1[4];
#pragma unroll
        for (int t = 0; t < 4; ++t) {
            b0[t] = (s0 < s_end) ? Bp[((size_t)t * KSTEPS + s0) * 64 + lane]
                                 : make_uint4(0, 0, 0, 0);
            b1[t] = (s0 + 1 < s_end) ? Bp[((size_t)t * KSTEPS + s0 + 1) * 64 + lane]
                                     : make_uint4(0, 0, 0, 0);
        }
        for (int s = s0; s < s_end; ++s) {
            uint4 bq[4];
#pragma unroll
            for (int t = 0; t < 4; ++t) {
                bq[t] = b0[t];
                b0[t] = b1[t];
                if (s + 2 < s_end) b1[t] = Bp[((size_t)t * KSTEPS + s + 2) * 64 + lane];
            }
            bf16x8 a = frag_from_lds(arow, s, quad);
#pragma unroll
            for (int t = 0; t < 4; ++t)
                acc[t] = __builtin_amdgcn_mfma_f32_16x16x32_bf16(
                    a, __builtin_bit_cast(bf16x8, bq[t]), acc[t], 0, 0, 0);
        }
#pragma unroll
        for (int t = 0; t < 4; ++t) red[(w * 4 + t) * 64 + lane] = acc[t];
        __syncthreads();
        if (w < 4) {
            f32x4 s = {0, 0, 0, 0};
#pragma unroll
            for (int g = 0; g < 16; ++g) s += red[(g * 4 + w) * 64 + lane];
            if (lane < 16) {
                const int co = w * 16 + lane;
#pragma unroll
                for (int i = 0; i < 4; ++i) {
                    int nn = base + i;
                    if (nn < nNodes) {
                        float res = s[i] + cb[co] + fb[co];
                        if (MODE == 2) res += x[nn * 64 + co];
                        out[nn * 64 + co] = res;
                    }
                }
            }
        }
    }
}

// ---------------------------------------------------------------------------
// Layer 0 (CIN=4). Register-resident bin scatter: lane = bin (8x8), moments in
// 4 VGPRs; per node 4 waves take edge quarters into 4 LDS copies, reduce, GEMM.
__global__ __launch_bounds__(1024, 4) void conv0_mfma(
    const float* __restrict__ x, const unsigned short* __restrict__ Wb,
    const float* __restrict__ cb, const float* __restrict__ fb, const float* __restrict__ fw,
    const int* __restrict__ offs, const int* __restrict__ csr_jk,
    const float2* __restrict__ csr_w, float* __restrict__ out, int nNodes) {
    constexpr int TM = 4;
    constexpr int KT = 256;
    constexpr int KSTEPS = 8;
    constexpr int RS = KT + 12;  // 268
    extern __shared__ float mom[];  // [16][RS]
    const int tid = threadIdx.x;
    const int w = tid >> 6;
    const int lane = tid & 63;
    const int node = w >> 2;
    const int q = w & 3;
    const int base = blockIdx.x * TM;
    const int n = base + node;

    {
        float4 z = make_float4(0.f, 0.f, 0.f, 0.f);
        float4* m4 = (float4*)mom;
        const int tot4 = 16 * RS / 4;
        for (int i = tid; i < tot4; i += 1024) m4[i] = z;
    }
    __syncthreads();

    // ---- register scatter (lane = bin)
    if (n < nNodes) {
        const int e0 = offs[n], e1 = offs[n + 1];
        const int len = e1 - e0;
        const int ql = (len + 3) >> 2;
        const int bs = e0 + q * ql;
        const int be = min(bs + ql, e1);
        const int iu_l = lane >> 3, iv_l = lane & 7;
        f32x4 v = {0, 0, 0, 0};
        for (int b = bs; b < be; b += 4) {
#pragma unroll
            for (int u = 0; u < 4; ++u) {
                int e = b + u;
                if (e >= be) break;
                int jk = csr_jk[e];
                float2 wv = csr_w[e];
                int j = jk & 0x1FFFF;
                int iu = (jk >> 20) & 7;
                int iv = (jk >> 23) & 7;
                float fu = wv.x, fv = wv.y;
                float wu = (iu_l == iu) ? (1.f - fu) : ((iu_l == iu + 1) ? fu : 0.f);
                float wvv = (iv_l == iv) ? (1.f - fv) : ((iv_l == iv + 1) ? fv : 0.f);
                float wgt = wu * wvv;
                const float4 xj = *(const float4*)(x + j * 4);
                v.x += wgt * xj.x;
                v.y += wgt * xj.y;
                v.z += wgt * xj.z;
                v.w += wgt * xj.w;
            }
        }
        ((float4*)(mom + (q * 4 + node) * RS))[lane] = *(float4*)&v;
    }
    __syncthreads();

    // ---- reduce 4 copies -> rows 0..3
    for (int idx = tid; idx < TM * 64; idx += 1024) {
        int r = idx >> 6, off = idx & 63;
        float4 s0 = ((float4*)(mom + (0 * 4 + r) * RS))[off];
        float4 s1 = ((float4*)(mom + (1 * 4 + r) * RS))[off];
        float4 s2 = ((float4*)(mom + (2 * 4 + r) * RS))[off];
        float4 s3 = ((float4*)(mom + (3 * 4 + r) * RS))[off];
        s0.x += s1.x + s2.x + s3.x;
        s0.y += s1.y + s2.y + s3.y;
        s0.z += s1.z + s2.z + s3.z;
        s0.w += s1.w + s2.w + s3.w;
        ((float4*)(mom + r * RS))[off] = s0;
    }
    __syncthreads();

    // ---- GEMM
    const int row = lane & 15;
    const int quad = lane >> 4;
    const float* arow = mom + (row & 3) * RS;
    if (w < 2) {
        const uint4* Bp = (const uint4*)Wb + (size_t)w * KSTEPS * 64;
        f32x4 acc = {0, 0, 0, 0};
        uint4 b0 = Bp[lane], b1 = Bp[64 + lane], b2 = Bp[128 + lane], b3 = Bp[192 + lane];
        for (int s = 0; s < KSTEPS; ++s) {
            uint4 bq = b0;
            b0 = b1; b1 = b2; b2 = b3;
            if (s + 4 < KSTEPS) b3 = Bp[(size_t)(s + 4) * 64 + lane];
            bf16x8 a = frag_from_lds(arow, s, quad);
            acc = __builtin_amdgcn_mfma_f32_16x16x32_bf16(a, __builtin_bit_cast(bf16x8, bq), acc,
                                                          0, 0, 0);
        }
        if (lane < 16) {
            const int co = w * 16 + lane;
#pragma unroll
            for (int i = 0; i < 4; ++i) {
                int nn = base + i;
                if (nn < nNodes) out[nn * 64 + 32 + co] = acc[i] + cb[co];
            }
        }
    } else if (w == 2 || w == 3) {
        // dense lin branch -> cols 0..31 (no relu on layer-0 input)
        const int co = lane & 31;
        const int r = (w - 2) * 2 + (lane >> 5);
        int nn = base + r;
        if (nn < nNodes) {
            const float4 xr = *(const float4*)(x + nn * 4);
            float sdot = xr.x * fw[co] + xr.y * fw[32 + co] + xr.z * fw[64 + co] +
                         xr.w * fw[96 + co] + fb[co];
            out[nn * 64 + co] = sdot;
        }
    }
}

extern "C" void kernel_launch(void* const* d_in, const int* in_sizes, int n_in,
                              void* d_out, int out_size, void* d_ws, size_t ws_size,
                              hipStream_t stream) {
    const float* pos = (const float*)d_in[0];
    const float* feat = (const float*)d_in[1];
    const int* ei = (const int*)d_in[2];
    const int* ej = (const int*)d_in[3];
    const float* cw0 = (const float*)d_in[4];
    const float* cb0 = (const float*)d_in[5];
    const float* fw0 = (const float*)d_in[6];
    const float* fb0 = (const float*)d_in[7];
    const float* cw1 = (const float*)d_in[8];
    const float* cb1 = (const float*)d_in[9];
    const float* fw1 = (const float*)d_in[10];
    const float* fb1 = (const float*)d_in[11];
    const float* cw2 = (const float*)d_in[12];
    const float* cb2 = (const float*)d_in[13];
    const float* fw2 = (const float*)d_in[14];
    const float* fb2 = (const float*)d_in[15];
    const float* cw3 = (const float*)d_in[16];
    const float* cb3 = (const float*)d_in[17];
    const float* fw3 = (const float*)d_in[18];
    const float* fb3 = (const float*)d_in[19];
    float* outp = (float*)d_out;

    const int N = in_sizes[0] / 2;
    const int E = in_sizes[2];

    char* wsp = (char*)d_ws;
    size_t off = 0;
    auto alloc = [&](size_t bytes) -> void* {
        void* p = wsp + off;
        off = (off + bytes + 255) & ~(size_t)255;
        return p;
    };
    int* counts = (int*)alloc((size_t)N * 4);
    int* offs = (int*)alloc((size_t)(N + 1) * 4);
    int* cursor = (int*)alloc((size_t)N * 4);
    int* csr_jk = (int*)alloc((size_t)E * 4);
    float2* csr_w = (float2*)alloc((size_t)E * 8);
    float* ansA = (float*)alloc((size_t)N * 64 * 4);
    float* ansB = (float*)alloc((size_t)N * 64 * 4);
    unsigned short* Wb0 = (unsigned short*)alloc((size_t)2 * 8 * 512 * 2);
    unsigned short* Wb1 = (unsigned short*)alloc((size_t)4 * 130 * 512 * 2);
    unsigned short* Wb2 = (unsigned short*)alloc((size_t)4 * 130 * 512 * 2);
    unsigned short* Wb3 = (unsigned short*)alloc((size_t)1 * 130 * 512 * 2);
    (void)ws_size;
    (void)n_in;
    (void)out_size;

    const int BIG_LDS = 8 * (65 * 64 + 12) * 4;    // 133504 B -> 1 block/CU, 16 waves
    const int SMALL_LDS = 16 * (64 * 4 + 12) * 4;  // 17152 B
    hipFuncSetAttribute((const void*)&conv64_mfma<1>,
                        hipFuncAttributeMaxDynamicSharedMemorySize, BIG_LDS);
    hipFuncSetAttribute((const void*)&conv64_mfma<2>,
                        hipFuncAttributeMaxDynamicSharedMemorySize, BIG_LDS);
    hipFuncSetAttribute((const void*)&conv64_mfma<3>,
                        hipFuncAttributeMaxDynamicSharedMemorySize, BIG_LDS);

    zero_ints<<<dim3((N + 255) / 256), dim3(256), 0, stream>>>(counts, N);
    repack_wb<<<dim3((2 * 8 * 512 + 255) / 256), dim3(256), 0, stream>>>(cw0, fw0, Wb0, 4, 32, 2, 0);
    repack_wb<<<dim3((4 * 130 * 512 + 255) / 256), dim3(256), 0, stream>>>(cw1, fw1, Wb1, 64, 64, 4, 1);
    repack_wb<<<dim3((4 * 130 * 512 + 255) / 256), dim3(256), 0, stream>>>(cw2, fw2, Wb2, 64, 64, 4, 1);
    repack_wb<<<dim3((1 * 130 * 512 + 255) / 256), dim3(256), 0, stream>>>(cw3, fw3, Wb3, 64, 2, 1, 1);
    edge_hist<<<dim3((E + 255) / 256), dim3(256), 0, stream>>>(ei, ej, counts, E);
    scan_kernel<<<dim3(1), dim3(1024), 0, stream>>>(counts, offs, cursor, N);
    edge_scatter<<<dim3((E + 255) / 256), dim3(256), 0, stream>>>(ei, ej, pos, cursor, csr_jk,
                                                                  csr_w, E);

    const int nb = (N + 3) / 4;
    conv0_mfma<<<dim3(nb), dim3(1024), SMALL_LDS, stream>>>(
        feat, Wb0, cb0, fb0, fw0, offs, csr_jk, csr_w, ansA, N);
    conv64_mfma<1><<<dim3(nb), dim3(1024), BIG_LDS, stream>>>(
        ansA, Wb1, cb1, fb1, offs, csr_jk, csr_w, ansB, N);
    conv64_mfma<2><<<dim3(nb), dim3(1024), BIG_LDS, stream>>>(
        ansB, Wb2, cb2, fb2, offs, csr_jk, csr_w, ansA, N);
    conv64_mfma<3><<<dim3(nb), dim3(1024), BIG_LDS, stream>>>(
        ansA, Wb3, cb3, fb3, offs, csr_jk, csr_w, outp, N);
}

// Round 8
// 1654.682 us; speedup vs baseline: 4.8193x; 1.3875x over previous
//
#include <hip/hip_runtime.h>
#include <math.h>

typedef __bf16 bf16x8 __attribute__((ext_vector_type(8)));
typedef float f32x4 __attribute__((ext_vector_type(4)));
typedef float f32x8 __attribute__((ext_vector_type(8)));

__device__ __forceinline__ float clampf(float x, float lo, float hi) {
    return fminf(fmaxf(x, lo), hi);
}

__global__ void zero_ints(int* __restrict__ p, int n) {
    int i = blockIdx.x * 256 + threadIdx.x;
    if (i < n) p[i] = 0;
}

// Pack W into MFMA B-frag layout, bf16.
// Wb[((t*KSTEPS + s)*64 + l)*8 + j] = W[k = s*32 + (l>>4)*8 + j][co = t*16 + (l&15)]
__global__ void repack_wb(const float* __restrict__ cw, const float* __restrict__ fw,
                          unsigned short* __restrict__ Wb, int CIN, int COUT, int COTILES,
                          int DENSE) {
    int idx = blockIdx.x * 256 + threadIdx.x;
    int KT = (DENSE ? 65 : 64) * CIN;
    int KSTEPS = KT / 32;
    int total = COTILES * KSTEPS * 512;
    if (idx >= total) return;
    int j = idx & 7;
    int l = (idx >> 3) & 63;
    int rest = idx >> 9;
    int s = rest % KSTEPS;
    int t = rest / KSTEPS;
    int k = s * 32 + (l >> 4) * 8 + j;
    int co = t * 16 + (l & 15);
    float v = 0.f;
    if (co < COUT) {
        if (k < 64 * CIN) v = cw[k * COUT + co];
        else v = fw[(k - 64 * CIN) * COUT + co];
    }
    __bf16 h = (__bf16)v;
    Wb[idx] = __builtin_bit_cast(unsigned short, h);
}

__global__ void edge_hist(const int* __restrict__ ei, const int* __restrict__ ej,
                          int* __restrict__ counts, int E) {
    int e = blockIdx.x * 256 + threadIdx.x;
    if (e >= E) return;
    int i = ei[e], j = ej[e];
    if (i != j) atomicAdd(&counts[i], 1);
}

__global__ __launch_bounds__(1024) void scan_kernel(const int* __restrict__ counts,
                                                    int* __restrict__ offs,
                                                    int* __restrict__ cursor, int N) {
    __shared__ int sums[1024];
    const int t = threadIdx.x;
    const int per = (N + 1023) / 1024;
    const int lo = t * per;
    const int hi = min(lo + per, N);
    int s = 0;
    for (int i = lo; i < hi; ++i) s += counts[i];
    sums[t] = s;
    __syncthreads();
    for (int d = 1; d < 1024; d <<= 1) {
        int v = (t >= d) ? sums[t - d] : 0;
        __syncthreads();
        sums[t] += v;
        __syncthreads();
    }
    int run = (t > 0) ? sums[t - 1] : 0;
    for (int i = lo; i < hi; ++i) {
        offs[i] = run;
        cursor[i] = run;
        run += counts[i];
    }
    if (t == 1023) offs[N] = sums[1023];
}

// csr_jk pack: j[0:17) | iu[20:23) | iv[23:26)
__global__ void edge_scatter(const int* __restrict__ ei, const int* __restrict__ ej,
                             const float* __restrict__ pos, int* __restrict__ cursor,
                             int* __restrict__ csr_jk, float2* __restrict__ csr_w, int E) {
    int e = blockIdx.x * 256 + threadIdx.x;
    if (e >= E) return;
    int i = ei[e], j = ej[e];
    if (i == j) return;
    float dx = clampf(pos[i * 2 + 0] - pos[j * 2 + 0], -1.f, 1.f);
    float dy = clampf(pos[i * 2 + 1] - pos[j * 2 + 1], -1.f, 1.f);
    float r = sqrtf(dx * dx + dy * dy + 1e-12f);
    float u = clampf(2.f * r - 1.f, -1.f, 1.f);
    float v = atan2f(dy, dx) * 0.3183098861837907f;  // / pi
    float tu = (u + 1.f) * 3.5f;
    float tv = (v + 1.f) * 3.5f;
    int iu = min(6, max(0, (int)floorf(tu)));
    int iv = min(6, max(0, (int)floorf(tv)));
    float fu = clampf(tu - (float)iu, 0.f, 1.f);
    float fv = clampf(tv - (float)iv, 0.f, 1.f);
    int p = atomicAdd(&cursor[i], 1);
    csr_jk[p] = j | (iu << 20) | (iv << 23);
    csr_w[p] = make_float2(fu, fv);
}

__device__ __forceinline__ bf16x8 frag_from_lds(const float* arow, int s, int quad) {
    const float4* ap = (const float4*)(arow + s * 32 + quad * 8);
    float4 a0 = ap[0], a1 = ap[1];
    f32x8 av = {a0.x, a0.y, a0.z, a0.w, a1.x, a1.y, a1.z, a1.w};
    return __builtin_convertvector(av, bf16x8);
}

// ---------------------------------------------------------------------------
// Layers 1..3 (CIN=64). 1024 threads = 16 waves, TM=8 nodes, SINGLE moment copy.
// Scatter: 2 parity waves per node; each walks the node's full edge list and
// applies only the 2 taps whose bin-row parity matches (p=0 -> even rows,
// p=1 -> odd rows). Disjoint addresses -> race-free plain RMW (no ds atomics:
// 3x slower, round 6). Then 16-way K-split MFMA GEMM, partials overwrite the
// dead moment region after a barrier.
// MODE 1: relu in, out = conv(+dense row) + cb + fb
// MODE 2: MODE1 + residual x
// MODE 3: relu in, COUT=2 (1 co-tile), /128
template <int MODE>
__global__ __launch_bounds__(1024, 4) void conv64_mfma(
    const float* __restrict__ x, const unsigned short* __restrict__ Wb,
    const float* __restrict__ cb, const float* __restrict__ fb,
    const int* __restrict__ offs, const int* __restrict__ csr_jk,
    const float2* __restrict__ csr_w, float* __restrict__ out, int nNodes) {
    constexpr int TM = 8;
    constexpr int KT = 65 * 64;      // 4160
    constexpr int KSTEPS = KT / 32;  // 130
    constexpr int RS = KT + 12;      // 4172
    extern __shared__ float mom[];   // [8][RS]
    const int tid = threadIdx.x;
    const int w = tid >> 6;
    const int lane = tid & 63;
    const int node = w >> 1;
    const int p = w & 1;  // tap-row parity
    const int base = blockIdx.x * TM;
    const int n = base + node;

    {  // zero moments
        float4 z = make_float4(0.f, 0.f, 0.f, 0.f);
        float4* m4 = (float4*)mom;
        const int tot4 = TM * RS / 4;
        for (int i = tid; i < tot4; i += 1024) m4[i] = z;
    }
    __syncthreads();

    // ---- scatter
    if (n < nNodes) {
        const int e0 = offs[n], e1 = offs[n + 1];
        float* momn = mom + node * RS;
        const int c = lane;
        for (int b = e0; b < e1; b += 8) {
            int jk[8];
            float fu[8], fv[8], xv[8];
#pragma unroll
            for (int u = 0; u < 8; ++u) {
                int e = b + u;
                bool ok = e < e1;
                int ee = ok ? e : e0;
                jk[u] = csr_jk[ee];
                float2 wv = csr_w[ee];
                fu[u] = wv.x;
                fv[u] = wv.y;
                xv[u] = ok ? 1.f : 0.f;
            }
#pragma unroll
            for (int u = 0; u < 8; ++u) {
                int j = jk[u] & 0x1FFFF;
                xv[u] *= fmaxf(x[j * 64 + c], 0.f);
            }
#pragma unroll
            for (int u = 0; u < 8; ++u) {
                int iu = (jk[u] >> 20) & 7;
                int iv = (jk[u] >> 23) & 7;
                bool sel = ((iu & 1) == p);
                int rowi = sel ? iu : iu + 1;       // parity-p rows only
                float wu = sel ? (1.f - fu[u]) : fu[u];
                float gv = 1.f - fv[u];
                float* pp = momn + (rowi * 8 + iv) * 64 + c;
                pp[0] += wu * gv * xv[u];
                pp[64] += wu * fv[u] * xv[u];
            }
        }
        if (p == 0) {  // dense row k = 4096 + lane
            momn[4096 + lane] = fmaxf(x[n * 64 + lane], 0.f);
        }
    }
    __syncthreads();

    // ---- GEMM: 16-way K-split; A rows 8..15 duplicate 0..7 (never stored)
    const int row = lane & 15;
    const int quad = lane >> 4;
    const float* arow = mom + (row & 7) * RS;
    constexpr int CHUNK = (KSTEPS + 15) / 16;  // 9
    const int s0 = w * CHUNK;
    const int s_end = min(s0 + CHUNK, KSTEPS);

    if (MODE == 3) {
        const uint4* Bp = (const uint4*)Wb;
        f32x4 acc = {0, 0, 0, 0};
        uint4 b0 = make_uint4(0, 0, 0, 0), b1 = b0, b2 = b0, b3 = b0;
        if (s0 + 0 < s_end) b0 = Bp[(size_t)(s0 + 0) * 64 + lane];
        if (s0 + 1 < s_end) b1 = Bp[(size_t)(s0 + 1) * 64 + lane];
        if (s0 + 2 < s_end) b2 = Bp[(size_t)(s0 + 2) * 64 + lane];
        if (s0 + 3 < s_end) b3 = Bp[(size_t)(s0 + 3) * 64 + lane];
        for (int s = s0; s < s_end; ++s) {
            uint4 bq = b0;
            b0 = b1; b1 = b2; b2 = b3;
            if (s + 4 < s_end) b3 = Bp[(size_t)(s + 4) * 64 + lane];
            bf16x8 a = frag_from_lds(arow, s, quad);
            acc = __builtin_amdgcn_mfma_f32_16x16x32_bf16(a, __builtin_bit_cast(bf16x8, bq), acc,
                                                          0, 0, 0);
        }
        __syncthreads();
        f32x4* red = (f32x4*)mom;
        red[w * 64 + lane] = acc;
        __syncthreads();
        if (w == 0) {
            f32x4 s = {0, 0, 0, 0};
#pragma unroll
            for (int g = 0; g < 16; ++g) s += red[g * 64 + lane];
            const int co = lane & 15;
            if (co < 2 && quad < 2) {
#pragma unroll
                for (int i = 0; i < 4; ++i) {
                    int nn = base + quad * 4 + i;
                    if (nn < nNodes) out[nn * 2 + co] = (s[i] + cb[co] + fb[co]) * (1.f / 128.f);
                }
            }
        }
    } else {
        const uint4* Bp = (const uint4*)Wb;
        f32x4 acc[4] = {{0, 0, 0, 0}, {0, 0, 0, 0}, {0, 0, 0, 0}, {0, 0, 0, 0}};
        uint4 b0[4], b1[4];
#pragma unroll
        for (int t = 0; t < 4; ++t) {
            b0[t] = (s0 < s_end) ? Bp[((size_t)t * KSTEPS + s0) * 64 + lane]
                                 : make_uint4(0, 0, 0, 0);
            b1[t] = (s0 + 1 < s_end) ? Bp[((size_t)t * KSTEPS + s0 + 1) * 64 + lane]
                                     : make_uint4(0, 0, 0, 0);
        }
        for (int s = s0; s < s_end; ++s) {
            uint4 bq[4];
#pragma unroll
            for (int t = 0; t < 4; ++t) {
                bq[t] = b0[t];
                b0[t] = b1[t];
                if (s + 2 < s_end) b1[t] = Bp[((size_t)t * KSTEPS + s + 2) * 64 + lane];
            }
            bf16x8 a = frag_from_lds(arow, s, quad);
#pragma unroll
            for (int t = 0; t < 4; ++t)
                acc[t] = __builtin_amdgcn_mfma_f32_16x16x32_bf16(
                    a, __builtin_bit_cast(bf16x8, bq[t]), acc[t], 0, 0, 0);
        }
        __syncthreads();  // moments dead -> reuse as reduce scratch
        f32x4* red = (f32x4*)mom;
#pragma unroll
        for (int t = 0; t < 4; ++t) red[(w * 4 + t) * 64 + lane] = acc[t];
        __syncthreads();
        if (w < 4) {
            f32x4 s = {0, 0, 0, 0};
#pragma unroll
            for (int g = 0; g < 16; ++g) s += red[(g * 4 + w) * 64 + lane];
            if (lane < 32) {
                const int co = w * 16 + (lane & 15);
#pragma unroll
                for (int i = 0; i < 4; ++i) {
                    int nn = base + quad * 4 + i;
                    if (nn < nNodes) {
                        float res = s[i] + cb[co] + fb[co];
                        if (MODE == 2) res += x[nn * 64 + co];
                        out[nn * 64 + co] = res;
                    }
                }
            }
        }
    }
}

// ---------------------------------------------------------------------------
// Layer 0 (CIN=4). TM=8. Register-resident bin scatter: lane = bin (8x8),
// moments in 4 VGPRs; 2 edge-half waves per node into 2 LDS copies, reduce,
// then MFMA GEMM (waves 0,1) + dense lin branch (waves 2..5).
__global__ __launch_bounds__(1024, 4) void conv0_mfma(
    const float* __restrict__ x, const unsigned short* __restrict__ Wb,
    const float* __restrict__ cb, const float* __restrict__ fb, const float* __restrict__ fw,
    const int* __restrict__ offs, const int* __restrict__ csr_jk,
    const float2* __restrict__ csr_w, float* __restrict__ out, int nNodes) {
    constexpr int TM = 8;
    constexpr int KT = 256;
    constexpr int KSTEPS = 8;
    constexpr int RS = KT + 12;     // 268
    extern __shared__ float mom[];  // [16][RS]: rows 0..7 copy0, 8..15 copy1
    const int tid = threadIdx.x;
    const int w = tid >> 6;
    const int lane = tid & 63;
    const int node = w >> 1;
    const int h = w & 1;
    const int base = blockIdx.x * TM;
    const int n = base + node;

    {
        float4 z = make_float4(0.f, 0.f, 0.f, 0.f);
        float4* m4 = (float4*)mom;
        const int tot4 = 16 * RS / 4;
        for (int i = tid; i < tot4; i += 1024) m4[i] = z;
    }
    __syncthreads();

    // ---- register scatter (lane = bin)
    if (n < nNodes) {
        const int e0 = offs[n], e1 = offs[n + 1];
        const int len = e1 - e0;
        const int hl = (len + 1) >> 1;
        const int bs = e0 + h * hl;
        const int be = min(bs + hl, e1);
        const int iu_l = lane >> 3, iv_l = lane & 7;
        f32x4 v = {0, 0, 0, 0};
        for (int b = bs; b < be; b += 4) {
#pragma unroll
            for (int u = 0; u < 4; ++u) {
                int e = b + u;
                if (e >= be) break;
                int jk = csr_jk[e];
                float2 wv = csr_w[e];
                int j = jk & 0x1FFFF;
                int iu = (jk >> 20) & 7;
                int iv = (jk >> 23) & 7;
                float fu = wv.x, fv = wv.y;
                float wu = (iu_l == iu) ? (1.f - fu) : ((iu_l == iu + 1) ? fu : 0.f);
                float wvv = (iv_l == iv) ? (1.f - fv) : ((iv_l == iv + 1) ? fv : 0.f);
                float wgt = wu * wvv;
                const float4 xj = *(const float4*)(x + j * 4);
                v.x += wgt * xj.x;
                v.y += wgt * xj.y;
                v.z += wgt * xj.z;
                v.w += wgt * xj.w;
            }
        }
        ((float4*)(mom + (h * 8 + node) * RS))[lane] = *(float4*)&v;
    }
    __syncthreads();

    // ---- reduce 2 copies -> rows 0..7
    for (int idx = tid; idx < TM * 64; idx += 1024) {
        int r = idx >> 6, off = idx & 63;
        float4 s0 = ((float4*)(mom + r * RS))[off];
        float4 s1 = ((float4*)(mom + (8 + r) * RS))[off];
        s0.x += s1.x;
        s0.y += s1.y;
        s0.z += s1.z;
        s0.w += s1.w;
        ((float4*)(mom + r * RS))[off] = s0;
    }
    __syncthreads();

    // ---- GEMM
    const int row = lane & 15;
    const int quad = lane >> 4;
    const float* arow = mom + (row & 7) * RS;
    if (w < 2) {
        const uint4* Bp = (const uint4*)Wb + (size_t)w * KSTEPS * 64;
        f32x4 acc = {0, 0, 0, 0};
        uint4 b0 = Bp[lane], b1 = Bp[64 + lane], b2 = Bp[128 + lane], b3 = Bp[192 + lane];
        for (int s = 0; s < KSTEPS; ++s) {
            uint4 bq = b0;
            b0 = b1; b1 = b2; b2 = b3;
            if (s + 4 < KSTEPS) b3 = Bp[(size_t)(s + 4) * 64 + lane];
            bf16x8 a = frag_from_lds(arow, s, quad);
            acc = __builtin_amdgcn_mfma_f32_16x16x32_bf16(a, __builtin_bit_cast(bf16x8, bq), acc,
                                                          0, 0, 0);
        }
        if (lane < 32) {
            const int co = w * 16 + (lane & 15);
#pragma unroll
            for (int i = 0; i < 4; ++i) {
                int nn = base + quad * 4 + i;
                if (nn < nNodes) out[nn * 64 + 32 + co] = acc[i] + cb[co];
            }
        }
    } else if (w >= 2 && w < 6) {
        // dense lin branch -> cols 0..31 (no relu on layer-0 input)
        const int co = lane & 31;
        const int r = (w - 2) * 2 + (lane >> 5);
        int nn = base + r;
        if (nn < nNodes) {
            const float4 xr = *(const float4*)(x + nn * 4);
            float sdot = xr.x * fw[co] + xr.y * fw[32 + co] + xr.z * fw[64 + co] +
                         xr.w * fw[96 + co] + fb[co];
            out[nn * 64 + co] = sdot;
        }
    }
}

extern "C" void kernel_launch(void* const* d_in, const int* in_sizes, int n_in,
                              void* d_out, int out_size, void* d_ws, size_t ws_size,
                              hipStream_t stream) {
    const float* pos = (const float*)d_in[0];
    const float* feat = (const float*)d_in[1];
    const int* ei = (const int*)d_in[2];
    const int* ej = (const int*)d_in[3];
    const float* cw0 = (const float*)d_in[4];
    const float* cb0 = (const float*)d_in[5];
    const float* fw0 = (const float*)d_in[6];
    const float* fb0 = (const float*)d_in[7];
    const float* cw1 = (const float*)d_in[8];
    const float* cb1 = (const float*)d_in[9];
    const float* fw1 = (const float*)d_in[10];
    const float* fb1 = (const float*)d_in[11];
    const float* cw2 = (const float*)d_in[12];
    const float* cb2 = (const float*)d_in[13];
    const float* fw2 = (const float*)d_in[14];
    const float* fb2 = (const float*)d_in[15];
    const float* cw3 = (const float*)d_in[16];
    const float* cb3 = (const float*)d_in[17];
    const float* fw3 = (const float*)d_in[18];
    const float* fb3 = (const float*)d_in[19];
    float* outp = (float*)d_out;

    const int N = in_sizes[0] / 2;
    const int E = in_sizes[2];

    char* wsp = (char*)d_ws;
    size_t off = 0;
    auto alloc = [&](size_t bytes) -> void* {
        void* p = wsp + off;
        off = (off + bytes + 255) & ~(size_t)255;
        return p;
    };
    int* counts = (int*)alloc((size_t)N * 4);
    int* offs = (int*)alloc((size_t)(N + 1) * 4);
    int* cursor = (int*)alloc((size_t)N * 4);
    int* csr_jk = (int*)alloc((size_t)E * 4);
    float2* csr_w = (float2*)alloc((size_t)E * 8);
    float* ansA = (float*)alloc((size_t)N * 64 * 4);
    float* ansB = (float*)alloc((size_t)N * 64 * 4);
    unsigned short* Wb0 = (unsigned short*)alloc((size_t)2 * 8 * 512 * 2);
    unsigned short* Wb1 = (unsigned short*)alloc((size_t)4 * 130 * 512 * 2);
    unsigned short* Wb2 = (unsigned short*)alloc((size_t)4 * 130 * 512 * 2);
    unsigned short* Wb3 = (unsigned short*)alloc((size_t)1 * 130 * 512 * 2);
    (void)ws_size;
    (void)n_in;
    (void)out_size;

    const int BIG_LDS = 8 * (65 * 64 + 12) * 4;    // 133504 B -> 1 block/CU, 16 waves
    const int SMALL_LDS = 16 * (64 * 4 + 12) * 4;  // 17152 B
    hipFuncSetAttribute((const void*)&conv64_mfma<1>,
                        hipFuncAttributeMaxDynamicSharedMemorySize, BIG_LDS);
    hipFuncSetAttribute((const void*)&conv64_mfma<2>,
                        hipFuncAttributeMaxDynamicSharedMemorySize, BIG_LDS);
    hipFuncSetAttribute((const void*)&conv64_mfma<3>,
                        hipFuncAttributeMaxDynamicSharedMemorySize, BIG_LDS);

    zero_ints<<<dim3((N + 255) / 256), dim3(256), 0, stream>>>(counts, N);
    repack_wb<<<dim3((2 * 8 * 512 + 255) / 256), dim3(256), 0, stream>>>(cw0, fw0, Wb0, 4, 32, 2, 0);
    repack_wb<<<dim3((4 * 130 * 512 + 255) / 256), dim3(256), 0, stream>>>(cw1, fw1, Wb1, 64, 64, 4, 1);
    repack_wb<<<dim3((4 * 130 * 512 + 255) / 256), dim3(256), 0, stream>>>(cw2, fw2, Wb2, 64, 64, 4, 1);
    repack_wb<<<dim3((1 * 130 * 512 + 255) / 256), dim3(256), 0, stream>>>(cw3, fw3, Wb3, 64, 2, 1, 1);
    edge_hist<<<dim3((E + 255) / 256), dim3(256), 0, stream>>>(ei, ej, counts, E);
    scan_kernel<<<dim3(1), dim3(1024), 0, stream>>>(counts, offs, cursor, N);
    edge_scatter<<<dim3((E + 255) / 256), dim3(256), 0, stream>>>(ei, ej, pos, cursor, csr_jk,
                                                                  csr_w, E);

    const int nb = (N + 7) / 8;
    conv0_mfma<<<dim3(nb), dim3(1024), SMALL_LDS, stream>>>(
        feat, Wb0, cb0, fb0, fw0, offs, csr_jk, csr_w, ansA, N);
    conv64_mfma<1><<<dim3(nb), dim3(1024), BIG_LDS, stream>>>(
        ansA, Wb1, cb1, fb1, offs, csr_jk, csr_w, ansB, N);
    conv64_mfma<2><<<dim3(nb), dim3(1024), BIG_LDS, stream>>>(
        ansB, Wb2, cb2, fb2, offs, csr_jk, csr_w, ansA, N);
    conv64_mfma<3><<<dim3(nb), dim3(1024), BIG_LDS, stream>>>(
        ansA, Wb3, cb3, fb3, offs, csr_jk, csr_w, outp, N);
}